// Round 8
// baseline (764.791 us; speedup 1.0000x reference)
//
#include <hip/hip_runtime.h>
#include <math.h>

#define BATCH 2048
#define SEQ   128
#define HID   512
#define OUTT  24
#define RPB   16              // batch rows per block; hi/lo = two M=16 tiles
#define NBLK  (BATCH/RPB)     // 128 blocks
#define TPB   1024            // 16 waves = 4/SIMD
#define NTW   2               // n-tiles per wave (16 waves x 2 = 32 n-tiles = 512 cols)
#define KTN   (HID/32)        // 16 k-tiles
#define LDSB_KT 3             // k-tiles resident in LDS (96 KB)
#define STR_KT  (KTN - LDSB_KT)             // 13 streamed from L2 per step
#define LDSB_BASE 0                         // kt 0..2 in LDS
#define STR_BASE  LDSB_KT                   // kt 3..15 streamed
#define ATILE 8192            // halves per A tile (16 rows x 512 k)

typedef _Float16 half8 __attribute__((ext_vector_type(8)));
typedef float   floatx4 __attribute__((ext_vector_type(4)));

__device__ __forceinline__ void mfma_hv(floatx4& c, half8 a, half8 b) {
    c = __builtin_amdgcn_mfma_f32_16x16x32_f16(a, b, c, 0, 0, 0);
}

// fast tanh: 1 - 2/(e^{2x}+1), e^{2x} = 2^(x*2/ln2). Saturates correctly.
__device__ __forceinline__ float ftanh(float x) {
    float e = __builtin_amdgcn_exp2f(x * 2.885390081777927f);
    float r = __builtin_amdgcn_rcpf(e + 1.0f);
    return fmaf(-2.0f, r, 1.0f);
}

// Pack W[j][k] (row-major HIDxHID fp32) into per-lane MFMA B-fragment layout,
// fp16: frag[(kt*32+nt)*64 + lane][8]; lane holds
// B[k = kt*32 + (lane>>4)*8 + jj][n = nt*16 + (lane&15)] = W[n][k].
__global__ __launch_bounds__(256) void pack_wfrag(const float* __restrict__ W,
                                                  _Float16* __restrict__ Bw)
{
    int id   = blockIdx.x * 256 + threadIdx.x;
    int lane = id & 63;
    int nt   = (id >> 6) & 31;
    int kt   = id >> 11;
    int n  = nt * 16 + (lane & 15);
    int k0 = kt * 32 + (lane >> 4) * 8;
    const float* src = W + (size_t)n * HID + k0;
    half8 v;
    #pragma unroll
    for (int j = 0; j < 8; j++) v[j] = (_Float16)src[j];
    *(half8*)&Bw[(size_t)id * 8] = v;
}

// Swizzled A layout per 16-row tile: el(m,k) = (k>>5)*512 + G*128 + ((m^G)<<3)
// + (k&7), G=(k>>3)&3. Tile 0 (offset 0) = hi(fp16) of batch rows 0..15;
// tile 1 (offset ATILE) = lo residual of the same rows.
// Reader lane (q,c), k-tile kt: contiguous aligned 16 B at kt*512 + q*128 + ((c^q)<<3).
__global__ __launch_bounds__(TPB)
__attribute__((amdgpu_waves_per_eu(4, 4)))
void rnn_persist(
    const float* __restrict__ x,
    const _Float16* __restrict__ BwE,
    const _Float16* __restrict__ BwD,
    const float* __restrict__ encWih, const float* __restrict__ encBih,
    const float* __restrict__ encBhh,
    const float* __restrict__ decWih, const float* __restrict__ decBih,
    const float* __restrict__ decBhh,
    const float* __restrict__ fcW, const float* __restrict__ fcB,
    float* __restrict__ out)
{
    __shared__ _Float16 A[2 * ATILE];           // 32 KB: [0]=hi tile, [ATILE]=lo tile
    __shared__ _Float16 BwL[LDSB_KT * 16384];   // 96 KB LDS-resident weight k-tiles
    __shared__ float    xs[RPB][SEQ];           // 8 KB
    __shared__ float    cWi[2][HID];            // 4 KB epilogue consts (0=enc,1=dec)
    __shared__ float    cBb[2][HID];            // 4 KB
    __shared__ float    dec_in_s[RPB];

    const int tid  = threadIdx.x;
    const int lane = tid & 63;
    const int wv   = tid >> 6;                  // 0..15
    const int row0 = blockIdx.x * RPB;
    const int c    = lane & 15;
    const int q    = lane >> 4;
    const int mB   = q * 4;                     // D rows owned: mB..mB+3 (0..15)

    const float fcb0 = fcB[0];

    // epilogue constants into LDS
    if (tid < HID) {
        cWi[0][tid] = encWih[tid];
        cBb[0][tid] = encBih[tid] + encBhh[tid];
        cWi[1][tid] = decWih[tid];
        cBb[1][tid] = decBih[tid] + decBhh[tid];
    }

    // preload x block-slice into LDS (coalesced float4): 16 rows x 128
    {
        const float4* xg = (const float4*)(x + (size_t)row0 * SEQ);
        if (tid < RPB * SEQ / 4) ((float4*)xs)[tid] = xg[tid];
    }

    // h0 = 0 (hi and lo tiles)
    for (int i = tid; i < 2 * ATILE / 2; i += TPB) ((int*)A)[i] = 0;

    // stage encoder LDS-resident weight k-tiles (96 KB)
    {
        const float4* src = (const float4*)(BwE + (size_t)LDSB_BASE * 16384);
        float4* dst = (float4*)BwL;
        #pragma unroll
        for (int i = 0; i < LDSB_KT * 16384 / 8 / TPB; i++)
            dst[i * TPB + tid] = src[i * TPB + tid];
    }

    const int    ldsAoff = q * 128 + ((c ^ q) << 3);
    const size_t bbase   = (size_t)(wv * NTW) * 512 + (size_t)lane * 8;
    const int    bbL     = wv * NTW * 512 + lane * 8;

    __syncthreads();

    for (int t = 0; t < SEQ + OUTT; t++) {
        const bool enc = (t < SEQ);
        const _Float16* __restrict__ Bw = enc ? BwE : BwD;

        if (t == SEQ) {   // one-time swap of LDS tiles to decoder weights
            const float4* src = (const float4*)(BwD + (size_t)LDSB_BASE * 16384);
            float4* dst = (float4*)BwL;
            #pragma unroll
            for (int i = 0; i < LDSB_KT * 16384 / 8 / TPB; i++)
                dst[i * TPB + tid] = src[i * TPB + tid];
            __syncthreads();
        }

        floatx4 accH[NTW], accL[NTW];
        #pragma unroll
        for (int i = 0; i < NTW; i++) {
            accH[i] = (floatx4){0.f, 0.f, 0.f, 0.f};
            accL[i] = (floatx4){0.f, 0.f, 0.f, 0.f};
        }

        // prime streamed-B prefetch (2 k-tiles deep)
        half8 bcur[NTW], bnxt[NTW];
        #pragma unroll
        for (int i = 0; i < NTW; i++) {
            bcur[i] = *(const half8*)&Bw[bbase + (size_t)STR_BASE * 16384 + i * 512];
            bnxt[i] = *(const half8*)&Bw[bbase + (size_t)(STR_BASE + 1) * 16384 + i * 512];
        }

        // LDS-resident k-tiles: hi and lo A-tiles share each B fragment
        #pragma unroll
        for (int kl = 0; kl < LDSB_KT; kl++) {
            half8 ah = *(const half8*)&A[(LDSB_BASE + kl) * 512 + ldsAoff];
            half8 al = *(const half8*)&A[ATILE + (LDSB_BASE + kl) * 512 + ldsAoff];
            #pragma unroll
            for (int i = 0; i < NTW; i++) {
                half8 b = *(const half8*)&BwL[kl * 16384 + bbL + i * 512];
                mfma_hv(accH[i], ah, b);
                mfma_hv(accL[i], al, b);
            }
        }

        // streamed k-tiles with rolling 2-deep prefetch
        #pragma unroll
        for (int s = 0; s < STR_KT; s++) {
            const int kt = STR_BASE + s;
            half8 bpre[NTW];
            if (s + 2 < STR_KT) {
                #pragma unroll
                for (int i = 0; i < NTW; i++)
                    bpre[i] = *(const half8*)&Bw[bbase + (size_t)(kt + 2) * 16384 + i * 512];
            }
            half8 ah = *(const half8*)&A[kt * 512 + ldsAoff];
            half8 al = *(const half8*)&A[ATILE + kt * 512 + ldsAoff];
            #pragma unroll
            for (int i = 0; i < NTW; i++) {
                mfma_hv(accH[i], ah, bcur[i]);
                mfma_hv(accL[i], al, bcur[i]);
            }
            #pragma unroll
            for (int i = 0; i < NTW; i++) {
                bcur[i] = bnxt[i];
                if (s + 2 < STR_KT) bnxt[i] = bpre[i];
            }
        }

        __syncthreads();   // all reads of A (h_t) complete before overwrite

        // ---- epilogue: sum hi+lo accumulators, tanh, write packed A in place ----
        float inp[4];
        if (enc) {
            #pragma unroll
            for (int r = 0; r < 4; r++) inp[r] = xs[mB + r][t];
        } else if (t == SEQ) {
            #pragma unroll
            for (int r = 0; r < 4; r++) inp[r] = xs[mB + r][SEQ - 1];
        } else {
            #pragma unroll
            for (int r = 0; r < 4; r++) inp[r] = dec_in_s[mB + r];
        }

        const int sel = enc ? 0 : 1;
        #pragma unroll
        for (int i = 0; i < NTW; i++) {
            int n = (wv * NTW + i) * 16 + c;   // this n is next step's k
            int G = (n >> 3) & 3;
            int base = (n >> 5) * 512 + G * 128 + (n & 7);
            float wi = cWi[sel][n];
            float bb = cBb[sel][n];
            #pragma unroll
            for (int r = 0; r < 4; r++) {
                int m = mB + r;
                float v = ftanh(accH[i][r] + accL[i][r] + inp[r] * wi + bb);
                _Float16 hh = (_Float16)v;
                _Float16 rs = (_Float16)(v - (float)hh);
                int off = base + ((m ^ G) << 3);
                A[off]         = hh;
                A[ATILE + off] = rs;
            }
        }
        __syncthreads();   // A (h_{t+1}) complete

        if (!enc) {
            // FC: wave wv reduces batch row wv (16 waves, 16 rows)
            const int m = wv;
            float sfc = 0.f;
            #pragma unroll
            for (int ii = 0; ii < HID / 64; ii++) {
                int k = ii * 64 + lane;
                int G = (k >> 3) & 3;
                int a0 = (k >> 5) * 512 + G * 128 + (k & 7) + ((m ^ G) << 3);
                float hv = (float)A[a0] + (float)A[ATILE + a0];
                sfc = fmaf(hv, fcW[k], sfc);
            }
            #pragma unroll
            for (int off = 32; off > 0; off >>= 1)
                sfc += __shfl_down(sfc, off, 64);
            if (lane == 0) {
                float o = sfc + fcb0;
                dec_in_s[m] = o;
                out[(size_t)(row0 + m) * OUTT + (t - SEQ)] = o;
            }
            __syncthreads();
        }
    }
}

extern "C" void kernel_launch(void* const* d_in, const int* in_sizes, int n_in,
                              void* d_out, int out_size, void* d_ws, size_t ws_size,
                              hipStream_t stream)
{
    const float* x        = (const float*)d_in[0];
    const float* enc_Wih  = (const float*)d_in[1];
    const float* enc_Whh  = (const float*)d_in[2];
    const float* enc_bih  = (const float*)d_in[3];
    const float* enc_bhh  = (const float*)d_in[4];
    const float* dec_Wih  = (const float*)d_in[5];
    const float* dec_Whh  = (const float*)d_in[6];
    const float* dec_bih  = (const float*)d_in[7];
    const float* dec_bhh  = (const float*)d_in[8];
    const float* fc_W     = (const float*)d_in[9];
    const float* fc_b     = (const float*)d_in[10];
    float* out = (float*)d_out;

    const size_t wfrag = (size_t)HID * HID;
    _Float16* BwE = (_Float16*)d_ws;
    _Float16* BwD = BwE + wfrag;

    pack_wfrag<<<HID * HID / (256 * 8), 256, 0, stream>>>(enc_Whh, BwE);
    pack_wfrag<<<HID * HID / (256 * 8), 256, 0, stream>>>(dec_Whh, BwD);

    rnn_persist<<<NBLK, TPB, 0, stream>>>(
        x, BwE, BwD,
        enc_Wih, enc_bih, enc_bhh,
        dec_Wih, dec_bih, dec_bhh,
        fc_W, fc_b, out);
}

// Round 10
// 749.865 us; speedup vs baseline: 1.0199x; 1.0199x over previous
//
#include <hip/hip_runtime.h>
#include <math.h>

#define BATCH 2048
#define SEQ   128
#define HID   512
#define OUTT  24
#define RPB   16              // batch rows per block; hi/lo = two M=16 tiles
#define NBLK  (BATCH/RPB)     // 128 blocks
#define TPB   1024            // 16 waves = 4/SIMD
#define NTW   2               // n-tiles per wave (16 waves x 2 = 32 n-tiles = 512 cols)
#define KTN   (HID/32)        // 16 k-tiles
#define LDSB_KT 3             // k-tiles resident in LDS (96 KB)
#define STR_KT  (KTN - LDSB_KT)             // 13 streamed from L2 per step
#define LDSB_BASE 0                         // kt 0..2 in LDS
#define STR_BASE  LDSB_KT                   // kt 3..15 streamed
#define ATILE 8192            // halves per A tile (16 rows x 512 k)
#define PFD 4                 // streamed prefetch depth: 4 tiles ~310 cy > L2 latency

typedef _Float16 half8 __attribute__((ext_vector_type(8)));
typedef float   floatx4 __attribute__((ext_vector_type(4)));

__device__ __forceinline__ void mfma_hv(floatx4& c, half8 a, half8 b) {
    c = __builtin_amdgcn_mfma_f32_16x16x32_f16(a, b, c, 0, 0, 0);
}

// fast tanh: 1 - 2/(e^{2x}+1), e^{2x} = 2^(x*2/ln2). Saturates correctly.
__device__ __forceinline__ float ftanh(float x) {
    float e = __builtin_amdgcn_exp2f(x * 2.885390081777927f);
    float r = __builtin_amdgcn_rcpf(e + 1.0f);
    return fmaf(-2.0f, r, 1.0f);
}

// Pack W[j][k] (row-major HIDxHID fp32) into per-lane MFMA B-fragment layout,
// fp16: frag[(kt*32+nt)*64 + lane][8]; lane holds
// B[k = kt*32 + (lane>>4)*8 + jj][n = nt*16 + (lane&15)] = W[n][k].
__global__ __launch_bounds__(256) void pack_wfrag(const float* __restrict__ W,
                                                  _Float16* __restrict__ Bw)
{
    int id   = blockIdx.x * 256 + threadIdx.x;
    int lane = id & 63;
    int nt   = (id >> 6) & 31;
    int kt   = id >> 11;
    int n  = nt * 16 + (lane & 15);
    int k0 = kt * 32 + (lane >> 4) * 8;
    const float* src = W + (size_t)n * HID + k0;
    half8 v;
    #pragma unroll
    for (int j = 0; j < 8; j++) v[j] = (_Float16)src[j];
    *(half8*)&Bw[(size_t)id * 8] = v;
}

// Swizzled A layout per 16-row tile: el(m,k) = (k>>5)*512 + G*128 + ((m^G)<<3)
// + (k&7), G=(k>>3)&3. Tile 0 (offset 0) = hi(fp16) of batch rows 0..15;
// tile 1 (offset ATILE) = lo residual of the same rows.
// Reader lane (q,c), k-tile kt: contiguous aligned 16 B at kt*512 + q*128 + ((c^q)<<3).
__global__ __launch_bounds__(TPB)
__attribute__((amdgpu_waves_per_eu(4, 4)))
void rnn_persist(
    const float* __restrict__ x,
    const _Float16* __restrict__ BwE,
    const _Float16* __restrict__ BwD,
    const float* __restrict__ encWih, const float* __restrict__ encBih,
    const float* __restrict__ encBhh,
    const float* __restrict__ decWih, const float* __restrict__ decBih,
    const float* __restrict__ decBhh,
    const float* __restrict__ fcW, const float* __restrict__ fcB,
    float* __restrict__ out)
{
    __shared__ _Float16 A[2 * ATILE];           // 32 KB: [0]=hi tile, [ATILE]=lo tile
    __shared__ _Float16 BwL[LDSB_KT * 16384];   // 96 KB LDS-resident weight k-tiles
    __shared__ float    xs[RPB][SEQ];           // 8 KB
    __shared__ float    dec_in_s[RPB];

    const int tid  = threadIdx.x;
    const int lane = tid & 63;
    const int wv   = tid >> 6;                  // 0..15
    const int row0 = blockIdx.x * RPB;
    const int c    = lane & 15;
    const int q    = lane >> 4;
    const int mB   = q * 4;                     // D rows owned: mB..mB+3 (0..15)

    const float fcb0 = fcB[0];

    // ---- t-invariant epilogue state, all in registers ----
    int   nIdx[NTW];
    int   moff[NTW][4];           // A write offsets (t-invariant)
    float wiR[NTW], bbR[NTW];     // swapped enc->dec once at t==SEQ
    #pragma unroll
    for (int i = 0; i < NTW; i++) {
        int n = (wv * NTW + i) * 16 + c;
        nIdx[i] = n;
        int G = (n >> 3) & 3;
        int base = (n >> 5) * 512 + G * 128 + (n & 7);
        #pragma unroll
        for (int r = 0; r < 4; r++)
            moff[i][r] = base + (((mB + r) ^ G) << 3);
        wiR[i] = encWih[n];
        bbR[i] = encBih[n] + encBhh[n];
    }
    // FC constants (wave wv reduces batch row wv)
    int   aFC[HID / 64];
    float fcw[HID / 64];
    #pragma unroll
    for (int ii = 0; ii < HID / 64; ii++) {
        int k = ii * 64 + lane;
        int G = (k >> 3) & 3;
        aFC[ii] = (k >> 5) * 512 + G * 128 + (k & 7) + ((wv ^ G) << 3);
        fcw[ii] = fcW[k];
    }

    // preload x block-slice into LDS (coalesced float4): 16 rows x 128
    {
        const float4* xg = (const float4*)(x + (size_t)row0 * SEQ);
        if (tid < RPB * SEQ / 4) ((float4*)xs)[tid] = xg[tid];
    }

    // h0 = 0 (hi and lo tiles)
    for (int i = tid; i < 2 * ATILE / 2; i += TPB) ((int*)A)[i] = 0;

    // stage encoder LDS-resident weight k-tiles (96 KB)
    {
        const float4* src = (const float4*)(BwE + (size_t)LDSB_BASE * 16384);
        float4* dst = (float4*)BwL;
        #pragma unroll
        for (int i = 0; i < LDSB_KT * 16384 / 8 / TPB; i++)
            dst[i * TPB + tid] = src[i * TPB + tid];
    }

    const int    ldsAoff = q * 128 + ((c ^ q) << 3);
    const size_t bbase   = (size_t)(wv * NTW) * 512 + (size_t)lane * 8;
    const int    bbL     = wv * NTW * 512 + lane * 8;

    __syncthreads();

    for (int t = 0; t < SEQ + OUTT; t++) {
        const bool enc = (t < SEQ);
        const _Float16* __restrict__ Bw = enc ? BwE : BwD;

        if (t == SEQ) {   // one-time swap to decoder weights (LDS tiles + consts)
            #pragma unroll
            for (int i = 0; i < NTW; i++) {
                wiR[i] = decWih[nIdx[i]];
                bbR[i] = decBih[nIdx[i]] + decBhh[nIdx[i]];
            }
            const float4* src = (const float4*)(BwD + (size_t)LDSB_BASE * 16384);
            float4* dst = (float4*)BwL;
            #pragma unroll
            for (int i = 0; i < LDSB_KT * 16384 / 8 / TPB; i++)
                dst[i * TPB + tid] = src[i * TPB + tid];
            __syncthreads();
        }

        floatx4 accH[NTW], accL[NTW];
        #pragma unroll
        for (int i = 0; i < NTW; i++) {
            accH[i] = (floatx4){0.f, 0.f, 0.f, 0.f};
            accL[i] = (floatx4){0.f, 0.f, 0.f, 0.f};
        }

        // streamed-B: 4-deep rolling prefetch (full unroll -> SSA renaming, no moves)
        half8 sb[STR_KT][NTW];
        #pragma unroll
        for (int p = 0; p < PFD; p++)
            #pragma unroll
            for (int i = 0; i < NTW; i++)
                sb[p][i] = *(const half8*)&Bw[bbase + (size_t)(STR_BASE + p) * 16384 + i * 512];

        __builtin_amdgcn_s_setprio(1);

        // LDS-resident k-tiles: hi and lo A-tiles share each B fragment
        #pragma unroll
        for (int kl = 0; kl < LDSB_KT; kl++) {
            half8 ah = *(const half8*)&A[(LDSB_BASE + kl) * 512 + ldsAoff];
            half8 al = *(const half8*)&A[ATILE + (LDSB_BASE + kl) * 512 + ldsAoff];
            #pragma unroll
            for (int i = 0; i < NTW; i++) {
                half8 b = *(const half8*)&BwL[kl * 16384 + bbL + i * 512];
                mfma_hv(accH[i], ah, b);
                mfma_hv(accL[i], al, b);
            }
        }

        // streamed k-tiles
        #pragma unroll
        for (int s = 0; s < STR_KT; s++) {
            const int kt = STR_BASE + s;
            if (s + PFD < STR_KT) {
                #pragma unroll
                for (int i = 0; i < NTW; i++)
                    sb[s + PFD][i] = *(const half8*)&Bw[bbase + (size_t)(kt + PFD) * 16384 + i * 512];
            }
            half8 ah = *(const half8*)&A[kt * 512 + ldsAoff];
            half8 al = *(const half8*)&A[ATILE + kt * 512 + ldsAoff];
            #pragma unroll
            for (int i = 0; i < NTW; i++) {
                mfma_hv(accH[i], ah, sb[s][i]);
                mfma_hv(accL[i], al, sb[s][i]);
            }
        }

        __builtin_amdgcn_s_setprio(0);

        __syncthreads();   // all reads of A (h_t) complete before overwrite

        // ---- epilogue: sum hi+lo accumulators, tanh, write packed A in place ----
        float inp[4];
        if (enc) {
            #pragma unroll
            for (int r = 0; r < 4; r++) inp[r] = xs[mB + r][t];
        } else if (t == SEQ) {
            #pragma unroll
            for (int r = 0; r < 4; r++) inp[r] = xs[mB + r][SEQ - 1];
        } else {
            #pragma unroll
            for (int r = 0; r < 4; r++) inp[r] = dec_in_s[mB + r];
        }

        #pragma unroll
        for (int i = 0; i < NTW; i++) {
            #pragma unroll
            for (int r = 0; r < 4; r++) {
                float v = ftanh(accH[i][r] + accL[i][r] + inp[r] * wiR[i] + bbR[i]);
                _Float16 hh = (_Float16)v;
                _Float16 rs = (_Float16)(v - (float)hh);
                A[moff[i][r]]         = hh;
                A[ATILE + moff[i][r]] = rs;
            }
        }
        __syncthreads();   // A (h_{t+1}) complete

        if (!enc) {
            // FC: wave wv reduces batch row wv (16 waves, 16 rows), consts in regs
            float sfc = 0.f;
            #pragma unroll
            for (int ii = 0; ii < HID / 64; ii++) {
                float hv = (float)A[aFC[ii]] + (float)A[ATILE + aFC[ii]];
                sfc = fmaf(hv, fcw[ii], sfc);
            }
            #pragma unroll
            for (int off = 32; off > 0; off >>= 1)
                sfc += __shfl_down(sfc, off, 64);
            if (lane == 0) {
                float o = sfc + fcb0;
                dec_in_s[wv] = o;
                out[(size_t)(row0 + wv) * OUTT + (t - SEQ)] = o;
            }
            __syncthreads();
        }
    }
}

extern "C" void kernel_launch(void* const* d_in, const int* in_sizes, int n_in,
                              void* d_out, int out_size, void* d_ws, size_t ws_size,
                              hipStream_t stream)
{
    const float* x        = (const float*)d_in[0];
    const float* enc_Wih  = (const float*)d_in[1];
    const float* enc_Whh  = (const float*)d_in[2];
    const float* enc_bih  = (const float*)d_in[3];
    const float* enc_bhh  = (const float*)d_in[4];
    const float* dec_Wih  = (const float*)d_in[5];
    const float* dec_Whh  = (const float*)d_in[6];
    const float* dec_bih  = (const float*)d_in[7];
    const float* dec_bhh  = (const float*)d_in[8];
    const float* fc_W     = (const float*)d_in[9];
    const float* fc_b     = (const float*)d_in[10];
    float* out = (float*)d_out;

    const size_t wfrag = (size_t)HID * HID;
    _Float16* BwE = (_Float16*)d_ws;
    _Float16* BwD = BwE + wfrag;

    pack_wfrag<<<HID * HID / (256 * 8), 256, 0, stream>>>(enc_Whh, BwE);
    pack_wfrag<<<HID * HID / (256 * 8), 256, 0, stream>>>(dec_Whh, BwD);

    rnn_persist<<<NBLK, TPB, 0, stream>>>(
        x, BwE, BwD,
        enc_Wih, enc_bih, enc_bhh,
        dec_Wih, dec_bih, dec_bhh,
        fc_W, fc_b, out);
}

// Round 11
// 623.183 us; speedup vs baseline: 1.2272x; 1.2033x over previous
//
#include <hip/hip_runtime.h>
#include <math.h>

#define BATCH 2048
#define SEQ   128
#define HID   512
#define OUTT  24
#define RPB   16              // batch rows per block = one M=16 MFMA tile (fp16 state)
#define NBLK  (BATCH/RPB)     // 128 blocks
#define TPB   1024            // 16 waves = 4/SIMD
#define NTW   2               // n-tiles per wave (16 waves x 2 = 32 n-tiles = 512 cols)
#define KTN   (HID/32)        // 16 k-tiles
#define LDSB_KT 4             // k-tiles resident in LDS (128 KB)
#define STR_KT  (KTN - LDSB_KT)             // 12 streamed from L2 per step
#define LDSB_BASE 0                         // kt 0..3 in LDS
#define STR_BASE  LDSB_KT                   // kt 4..15 streamed
#define ATILE 8192            // halves in A tile (16 rows x 512 k)
#define PFD 4                 // streamed prefetch depth

typedef _Float16 half8 __attribute__((ext_vector_type(8)));
typedef float   floatx4 __attribute__((ext_vector_type(4)));

__device__ __forceinline__ void mfma_hv(floatx4& c, half8 a, half8 b) {
    c = __builtin_amdgcn_mfma_f32_16x16x32_f16(a, b, c, 0, 0, 0);
}

// fast tanh: 1 - 2/(e^{2x}+1), e^{2x} = 2^(x*2/ln2). Saturates correctly.
__device__ __forceinline__ float ftanh(float x) {
    float e = __builtin_amdgcn_exp2f(x * 2.885390081777927f);
    float r = __builtin_amdgcn_rcpf(e + 1.0f);
    return fmaf(-2.0f, r, 1.0f);
}

// Pack W[j][k] (row-major HIDxHID fp32) into per-lane MFMA B-fragment layout,
// fp16: frag[(kt*32+nt)*64 + lane][8]; lane holds
// B[k = kt*32 + (lane>>4)*8 + jj][n = nt*16 + (lane&15)] = W[n][k].
__global__ __launch_bounds__(256) void pack_wfrag(const float* __restrict__ W,
                                                  _Float16* __restrict__ Bw)
{
    int id   = blockIdx.x * 256 + threadIdx.x;
    int lane = id & 63;
    int nt   = (id >> 6) & 31;
    int kt   = id >> 11;
    int n  = nt * 16 + (lane & 15);
    int k0 = kt * 32 + (lane >> 4) * 8;
    const float* src = W + (size_t)n * HID + k0;
    half8 v;
    #pragma unroll
    for (int j = 0; j < 8; j++) v[j] = (_Float16)src[j];
    *(half8*)&Bw[(size_t)id * 8] = v;
}

// Swizzled A layout: el(m,k) = (k>>5)*512 + G*128 + ((m^G)<<3) + (k&7), G=(k>>3)&3.
// Single fp16 state tile (lo residual dropped: measured absmax was at the bf16
// comparison floor; threshold has 8x headroom).
// Reader lane (q,c), k-tile kt: contiguous aligned 16 B at kt*512 + q*128 + ((c^q)<<3).
__global__ __launch_bounds__(TPB)
__attribute__((amdgpu_waves_per_eu(4, 4)))
void rnn_persist(
    const float* __restrict__ x,
    const _Float16* __restrict__ BwE,
    const _Float16* __restrict__ BwD,
    const float* __restrict__ encWih, const float* __restrict__ encBih,
    const float* __restrict__ encBhh,
    const float* __restrict__ decWih, const float* __restrict__ decBih,
    const float* __restrict__ decBhh,
    const float* __restrict__ fcW, const float* __restrict__ fcB,
    float* __restrict__ out)
{
    __shared__ _Float16 A[ATILE];               // 16 KB fp16 h state
    __shared__ _Float16 BwL[LDSB_KT * 16384];   // 128 KB LDS-resident weight k-tiles
    __shared__ float    xs[RPB][SEQ];           // 8 KB
    __shared__ float    dec_in_s[RPB];

    const int tid  = threadIdx.x;
    const int lane = tid & 63;
    const int wv   = tid >> 6;                  // 0..15
    const int row0 = blockIdx.x * RPB;
    const int c    = lane & 15;
    const int q    = lane >> 4;
    const int mB   = q * 4;                     // D rows owned: mB..mB+3 (0..15)

    const float fcb0 = fcB[0];

    // ---- t-invariant epilogue state, all in registers ----
    int   nIdx[NTW];
    int   moff[NTW][4];           // A write offsets (t-invariant)
    float wiR[NTW], bbR[NTW];     // swapped enc->dec once at t==SEQ
    #pragma unroll
    for (int i = 0; i < NTW; i++) {
        int n = (wv * NTW + i) * 16 + c;
        nIdx[i] = n;
        int G = (n >> 3) & 3;
        int base = (n >> 5) * 512 + G * 128 + (n & 7);
        #pragma unroll
        for (int r = 0; r < 4; r++)
            moff[i][r] = base + (((mB + r) ^ G) << 3);
        wiR[i] = encWih[n];
        bbR[i] = encBih[n] + encBhh[n];
    }
    // FC constants (wave wv reduces batch row wv)
    int   aFC[HID / 64];
    float fcw[HID / 64];
    #pragma unroll
    for (int ii = 0; ii < HID / 64; ii++) {
        int k = ii * 64 + lane;
        int G = (k >> 3) & 3;
        aFC[ii] = (k >> 5) * 512 + G * 128 + (k & 7) + ((wv ^ G) << 3);
        fcw[ii] = fcW[k];
    }

    // preload x block-slice into LDS (coalesced float4): 16 rows x 128
    {
        const float4* xg = (const float4*)(x + (size_t)row0 * SEQ);
        if (tid < RPB * SEQ / 4) ((float4*)xs)[tid] = xg[tid];
    }

    // h0 = 0
    for (int i = tid; i < ATILE / 2; i += TPB) ((int*)A)[i] = 0;

    // stage encoder LDS-resident weight k-tiles (128 KB)
    {
        const float4* src = (const float4*)(BwE + (size_t)LDSB_BASE * 16384);
        float4* dst = (float4*)BwL;
        #pragma unroll
        for (int i = 0; i < LDSB_KT * 16384 / 8 / TPB; i++)
            dst[i * TPB + tid] = src[i * TPB + tid];
    }

    const int    ldsAoff = q * 128 + ((c ^ q) << 3);
    const size_t bbase   = (size_t)(wv * NTW) * 512 + (size_t)lane * 8;
    const int    bbL     = wv * NTW * 512 + lane * 8;

    __syncthreads();

    for (int t = 0; t < SEQ + OUTT; t++) {
        const bool enc = (t < SEQ);
        const _Float16* __restrict__ Bw = enc ? BwE : BwD;

        if (t == SEQ) {   // one-time swap to decoder weights (LDS tiles + consts)
            #pragma unroll
            for (int i = 0; i < NTW; i++) {
                wiR[i] = decWih[nIdx[i]];
                bbR[i] = decBih[nIdx[i]] + decBhh[nIdx[i]];
            }
            const float4* src = (const float4*)(BwD + (size_t)LDSB_BASE * 16384);
            float4* dst = (float4*)BwL;
            #pragma unroll
            for (int i = 0; i < LDSB_KT * 16384 / 8 / TPB; i++)
                dst[i * TPB + tid] = src[i * TPB + tid];
            __syncthreads();
        }

        floatx4 acc[NTW];
        #pragma unroll
        for (int i = 0; i < NTW; i++) acc[i] = (floatx4){0.f, 0.f, 0.f, 0.f};

        // streamed-B: PFD-deep rolling prefetch (full unroll -> SSA renaming)
        half8 sb[STR_KT][NTW];
        #pragma unroll
        for (int p = 0; p < PFD; p++)
            #pragma unroll
            for (int i = 0; i < NTW; i++)
                sb[p][i] = *(const half8*)&Bw[bbase + (size_t)(STR_BASE + p) * 16384 + i * 512];

        __builtin_amdgcn_s_setprio(1);

        // LDS-resident k-tiles
        #pragma unroll
        for (int kl = 0; kl < LDSB_KT; kl++) {
            half8 a = *(const half8*)&A[(LDSB_BASE + kl) * 512 + ldsAoff];
            #pragma unroll
            for (int i = 0; i < NTW; i++) {
                half8 b = *(const half8*)&BwL[kl * 16384 + bbL + i * 512];
                mfma_hv(acc[i], a, b);
            }
        }

        // streamed k-tiles
        #pragma unroll
        for (int s = 0; s < STR_KT; s++) {
            const int kt = STR_BASE + s;
            if (s + PFD < STR_KT) {
                #pragma unroll
                for (int i = 0; i < NTW; i++)
                    sb[s + PFD][i] = *(const half8*)&Bw[bbase + (size_t)(kt + PFD) * 16384 + i * 512];
            }
            half8 a = *(const half8*)&A[kt * 512 + ldsAoff];
            #pragma unroll
            for (int i = 0; i < NTW; i++)
                mfma_hv(acc[i], a, sb[s][i]);
        }

        __builtin_amdgcn_s_setprio(0);

        __syncthreads();   // all reads of A (h_t) complete before overwrite

        // ---- epilogue: tanh, write fp16 A in place ----
        float inp[4];
        if (enc) {
            #pragma unroll
            for (int r = 0; r < 4; r++) inp[r] = xs[mB + r][t];
        } else if (t == SEQ) {
            #pragma unroll
            for (int r = 0; r < 4; r++) inp[r] = xs[mB + r][SEQ - 1];
        } else {
            #pragma unroll
            for (int r = 0; r < 4; r++) inp[r] = dec_in_s[mB + r];
        }

        #pragma unroll
        for (int i = 0; i < NTW; i++) {
            #pragma unroll
            for (int r = 0; r < 4; r++) {
                float v = ftanh(acc[i][r] + inp[r] * wiR[i] + bbR[i]);
                A[moff[i][r]] = (_Float16)v;
            }
        }
        __syncthreads();   // A (h_{t+1}) complete

        if (!enc) {
            // FC: wave wv reduces batch row wv (16 waves, 16 rows), consts in regs
            float sfc = 0.f;
            #pragma unroll
            for (int ii = 0; ii < HID / 64; ii++)
                sfc = fmaf((float)A[aFC[ii]], fcw[ii], sfc);
            #pragma unroll
            for (int off = 32; off > 0; off >>= 1)
                sfc += __shfl_down(sfc, off, 64);
            if (lane == 0) {
                float o = sfc + fcb0;
                dec_in_s[wv] = o;
                out[(size_t)(row0 + wv) * OUTT + (t - SEQ)] = o;
            }
            __syncthreads();
        }
    }
}

extern "C" void kernel_launch(void* const* d_in, const int* in_sizes, int n_in,
                              void* d_out, int out_size, void* d_ws, size_t ws_size,
                              hipStream_t stream)
{
    const float* x        = (const float*)d_in[0];
    const float* enc_Wih  = (const float*)d_in[1];
    const float* enc_Whh  = (const float*)d_in[2];
    const float* enc_bih  = (const float*)d_in[3];
    const float* enc_bhh  = (const float*)d_in[4];
    const float* dec_Wih  = (const float*)d_in[5];
    const float* dec_Whh  = (const float*)d_in[6];
    const float* dec_bih  = (const float*)d_in[7];
    const float* dec_bhh  = (const float*)d_in[8];
    const float* fc_W     = (const float*)d_in[9];
    const float* fc_b     = (const float*)d_in[10];
    float* out = (float*)d_out;

    const size_t wfrag = (size_t)HID * HID;
    _Float16* BwE = (_Float16*)d_ws;
    _Float16* BwD = BwE + wfrag;

    pack_wfrag<<<HID * HID / (256 * 8), 256, 0, stream>>>(enc_Whh, BwE);
    pack_wfrag<<<HID * HID / (256 * 8), 256, 0, stream>>>(dec_Whh, BwD);

    rnn_persist<<<NBLK, TPB, 0, stream>>>(
        x, BwE, BwD,
        enc_Wih, enc_bih, enc_bhh,
        dec_Wih, dec_bih, dec_bhh,
        fc_W, fc_b, out);
}

// Round 12
// 596.623 us; speedup vs baseline: 1.2819x; 1.0445x over previous
//
#include <hip/hip_runtime.h>
#include <math.h>

#define BATCH 2048
#define SEQ   128
#define HID   512
#define OUTT  24
#define RPB   16              // batch rows per block = one M=16 MFMA tile (fp16 state)
#define NBLK  (BATCH/RPB)     // 128 blocks
#define TPB   1024            // 16 waves = 4/SIMD
#define NTW   2               // n-tiles per wave (16 waves x 2 = 32 n-tiles = 512 cols)
#define KTN   (HID/32)        // 16 k-tiles
#define LDSB_KT 3             // k-tiles resident in LDS (96 KB; A dbuf took 16 KB)
#define STR_KT  (KTN - LDSB_KT)             // 13 streamed from L2 per step
#define LDSB_BASE 0                         // kt 0..2 in LDS
#define STR_BASE  LDSB_KT                   // kt 3..15 streamed
#define ATILE 8192            // halves in one A tile (16 rows x 512 k)
#define PFD   4               // rolling prefetch lookahead inside MFMA phase
#define PRIME 2               // tiles primed during PREVIOUS step's epilogue

typedef _Float16 half8 __attribute__((ext_vector_type(8)));
typedef float   floatx4 __attribute__((ext_vector_type(4)));

__device__ __forceinline__ void mfma_hv(floatx4& c, half8 a, half8 b) {
    c = __builtin_amdgcn_mfma_f32_16x16x32_f16(a, b, c, 0, 0, 0);
}

// fast tanh: 1 - 2/(e^{2x}+1), e^{2x} = 2^(x*2/ln2). Saturates correctly.
__device__ __forceinline__ float ftanh(float x) {
    float e = __builtin_amdgcn_exp2f(x * 2.885390081777927f);
    float r = __builtin_amdgcn_rcpf(e + 1.0f);
    return fmaf(-2.0f, r, 1.0f);
}

// Pack W[j][k] (row-major HIDxHID fp32) into per-lane MFMA B-fragment layout,
// fp16: frag[(kt*32+nt)*64 + lane][8]; lane holds
// B[k = kt*32 + (lane>>4)*8 + jj][n = nt*16 + (lane&15)] = W[n][k].
__global__ __launch_bounds__(256) void pack_wfrag(const float* __restrict__ W,
                                                  _Float16* __restrict__ Bw)
{
    int id   = blockIdx.x * 256 + threadIdx.x;
    int lane = id & 63;
    int nt   = (id >> 6) & 31;
    int kt   = id >> 11;
    int n  = nt * 16 + (lane & 15);
    int k0 = kt * 32 + (lane >> 4) * 8;
    const float* src = W + (size_t)n * HID + k0;
    half8 v;
    #pragma unroll
    for (int j = 0; j < 8; j++) v[j] = (_Float16)src[j];
    *(half8*)&Bw[(size_t)id * 8] = v;
}

// Swizzled A layout: el(m,k) = (k>>5)*512 + G*128 + ((m^G)<<3) + (k&7), G=(k>>3)&3.
// Double-buffered fp16 state: MFMA reads A[cur], epilogue writes A[cur^1] ->
// NO mid-step barrier; one barrier per encode step.
// Reader lane (q,c), k-tile kt: contiguous aligned 16 B at kt*512 + q*128 + ((c^q)<<3).
__global__ __launch_bounds__(TPB)
__attribute__((amdgpu_waves_per_eu(4, 4)))
void rnn_persist(
    const float* __restrict__ x,
    const _Float16* __restrict__ BwE,
    const _Float16* __restrict__ BwD,
    const float* __restrict__ encWih, const float* __restrict__ encBih,
    const float* __restrict__ encBhh,
    const float* __restrict__ decWih, const float* __restrict__ decBih,
    const float* __restrict__ decBhh,
    const float* __restrict__ fcW, const float* __restrict__ fcB,
    float* __restrict__ out)
{
    __shared__ _Float16 A[2][ATILE];            // 32 KB double-buffered h state
    __shared__ _Float16 BwL[LDSB_KT * 16384];   // 96 KB LDS-resident weight k-tiles
    __shared__ float    xs[RPB][SEQ];           // 8 KB
    __shared__ float    dec_in_s[RPB];

    const int tid  = threadIdx.x;
    const int lane = tid & 63;
    const int wv   = tid >> 6;                  // 0..15
    const int row0 = blockIdx.x * RPB;
    const int c    = lane & 15;
    const int q    = lane >> 4;
    const int mB   = q * 4;                     // D rows owned: mB..mB+3 (0..15)

    const float fcb0 = fcB[0];

    // ---- t-invariant epilogue state, all in registers ----
    int   nIdx[NTW];
    int   moff[NTW][4];           // A write offsets (t-invariant)
    float wiR[NTW], bbR[NTW];     // swapped enc->dec once at t==SEQ
    #pragma unroll
    for (int i = 0; i < NTW; i++) {
        int n = (wv * NTW + i) * 16 + c;
        nIdx[i] = n;
        int G = (n >> 3) & 3;
        int base = (n >> 5) * 512 + G * 128 + (n & 7);
        #pragma unroll
        for (int r = 0; r < 4; r++)
            moff[i][r] = base + (((mB + r) ^ G) << 3);
        wiR[i] = encWih[n];
        bbR[i] = encBih[n] + encBhh[n];
    }
    // FC constants (wave wv reduces batch row wv)
    int   aFC[HID / 64];
    float fcw[HID / 64];
    #pragma unroll
    for (int ii = 0; ii < HID / 64; ii++) {
        int k = ii * 64 + lane;
        int G = (k >> 3) & 3;
        aFC[ii] = (k >> 5) * 512 + G * 128 + (k & 7) + ((wv ^ G) << 3);
        fcw[ii] = fcW[k];
    }

    // preload x block-slice into LDS (coalesced float4): 16 rows x 128
    {
        const float4* xg = (const float4*)(x + (size_t)row0 * SEQ);
        if (tid < RPB * SEQ / 4) ((float4*)xs)[tid] = xg[tid];
    }

    // h0 = 0
    for (int i = tid; i < ATILE / 2; i += TPB) ((int*)A[0])[i] = 0;

    // stage encoder LDS-resident weight k-tiles (96 KB)
    {
        const float4* src = (const float4*)(BwE + (size_t)LDSB_BASE * 16384);
        float4* dst = (float4*)BwL;
        #pragma unroll
        for (int i = 0; i < LDSB_KT * 16384 / 8 / TPB; i++)
            dst[i * TPB + tid] = src[i * TPB + tid];
    }

    const int    ldsAoff = q * 128 + ((c ^ q) << 3);
    const size_t bbase   = (size_t)(wv * NTW) * 512 + (size_t)lane * 8;
    const int    bbL     = wv * NTW * 512 + lane * 8;

    // streamed-B register file; entries written in fully-unrolled loops only
    half8 sb[STR_KT][NTW];
    // prime first PRIME tiles for t=0
    #pragma unroll
    for (int p = 0; p < PRIME; p++)
        #pragma unroll
        for (int i = 0; i < NTW; i++)
            sb[p][i] = *(const half8*)&BwE[bbase + (size_t)(STR_BASE + p) * 16384 + i * 512];

    __syncthreads();

    int cur = 0;
    for (int t = 0; t < SEQ + OUTT; t++) {
        const bool enc = (t < SEQ);
        const _Float16* __restrict__ Bw = enc ? BwE : BwD;

        if (t == SEQ) {   // one-time swap to decoder weights (LDS tiles + consts)
            #pragma unroll
            for (int i = 0; i < NTW; i++) {
                wiR[i] = decWih[nIdx[i]];
                bbR[i] = decBih[nIdx[i]] + decBhh[nIdx[i]];
            }
            const float4* src = (const float4*)(BwD + (size_t)LDSB_BASE * 16384);
            float4* dst = (float4*)BwL;
            #pragma unroll
            for (int i = 0; i < LDSB_KT * 16384 / 8 / TPB; i++)
                dst[i * TPB + tid] = src[i * TPB + tid];
            __syncthreads();
        }

        floatx4 acc[NTW];
        #pragma unroll
        for (int i = 0; i < NTW; i++) acc[i] = (floatx4){0.f, 0.f, 0.f, 0.f};

        __builtin_amdgcn_s_setprio(1);

        // extend lookahead PRIME -> PFD at phase start
        #pragma unroll
        for (int p = PRIME; p < PFD; p++)
            #pragma unroll
            for (int i = 0; i < NTW; i++)
                sb[p][i] = *(const half8*)&Bw[bbase + (size_t)(STR_BASE + p) * 16384 + i * 512];

        // LDS-resident k-tiles (reads A[cur])
        #pragma unroll
        for (int kl = 0; kl < LDSB_KT; kl++) {
            half8 a = *(const half8*)&A[cur][(LDSB_BASE + kl) * 512 + ldsAoff];
            #pragma unroll
            for (int i = 0; i < NTW; i++) {
                half8 b = *(const half8*)&BwL[kl * 16384 + bbL + i * 512];
                mfma_hv(acc[i], a, b);
            }
        }

        // streamed k-tiles with rolling prefetch
        #pragma unroll
        for (int s = 0; s < STR_KT; s++) {
            const int kt = STR_BASE + s;
            if (s + PFD < STR_KT) {
                #pragma unroll
                for (int i = 0; i < NTW; i++)
                    sb[s + PFD][i] = *(const half8*)&Bw[bbase + (size_t)(kt + PFD) * 16384 + i * 512];
            }
            half8 a = *(const half8*)&A[cur][kt * 512 + ldsAoff];
            #pragma unroll
            for (int i = 0; i < NTW; i++)
                mfma_hv(acc[i], a, sb[s][i]);
        }

        __builtin_amdgcn_s_setprio(0);

        // ---- epilogue (NO barrier before it: writes go to A[nxt]) ----
        const int nxt = cur ^ 1;

        // prime next step's first PRIME streamed tiles NOW -> L2 latency hides
        // under the tanh VALU below instead of stalling at next loop top.
        {
            const _Float16* __restrict__ Bwn = (t + 1 < SEQ) ? BwE : BwD;
            #pragma unroll
            for (int p = 0; p < PRIME; p++)
                #pragma unroll
                for (int i = 0; i < NTW; i++)
                    sb[p][i] = *(const half8*)&Bwn[bbase + (size_t)(STR_BASE + p) * 16384 + i * 512];
        }

        float inp[4];
        if (enc) {
            #pragma unroll
            for (int r = 0; r < 4; r++) inp[r] = xs[mB + r][t];
        } else if (t == SEQ) {
            #pragma unroll
            for (int r = 0; r < 4; r++) inp[r] = xs[mB + r][SEQ - 1];
        } else {
            #pragma unroll
            for (int r = 0; r < 4; r++) inp[r] = dec_in_s[mB + r];
        }

        #pragma unroll
        for (int i = 0; i < NTW; i++) {
            #pragma unroll
            for (int r = 0; r < 4; r++) {
                float v = ftanh(acc[i][r] + inp[r] * wiR[i] + bbR[i]);
                A[nxt][moff[i][r]] = (_Float16)v;
            }
        }
        __syncthreads();   // A[nxt] complete (single barrier per encode step)

        if (!enc) {
            // FC: wave wv reduces batch row wv (16 waves, 16 rows), consts in regs
            const _Float16* An = A[nxt];
            float sfc = 0.f;
            #pragma unroll
            for (int ii = 0; ii < HID / 64; ii++)
                sfc = fmaf((float)An[aFC[ii]], fcw[ii], sfc);
            #pragma unroll
            for (int off = 32; off > 0; off >>= 1)
                sfc += __shfl_down(sfc, off, 64);
            if (lane == 0) {
                float o = sfc + fcb0;
                dec_in_s[wv] = o;
                out[(size_t)(row0 + wv) * OUTT + (t - SEQ)] = o;
            }
            __syncthreads();   // dec_in_s ready for next step's epilogue
        }
        cur = nxt;
    }
}

extern "C" void kernel_launch(void* const* d_in, const int* in_sizes, int n_in,
                              void* d_out, int out_size, void* d_ws, size_t ws_size,
                              hipStream_t stream)
{
    const float* x        = (const float*)d_in[0];
    const float* enc_Wih  = (const float*)d_in[1];
    const float* enc_Whh  = (const float*)d_in[2];
    const float* enc_bih  = (const float*)d_in[3];
    const float* enc_bhh  = (const float*)d_in[4];
    const float* dec_Wih  = (const float*)d_in[5];
    const float* dec_Whh  = (const float*)d_in[6];
    const float* dec_bih  = (const float*)d_in[7];
    const float* dec_bhh  = (const float*)d_in[8];
    const float* fc_W     = (const float*)d_in[9];
    const float* fc_b     = (const float*)d_in[10];
    float* out = (float*)d_out;

    const size_t wfrag = (size_t)HID * HID;
    _Float16* BwE = (_Float16*)d_ws;
    _Float16* BwD = BwE + wfrag;

    pack_wfrag<<<HID * HID / (256 * 8), 256, 0, stream>>>(enc_Whh, BwE);
    pack_wfrag<<<HID * HID / (256 * 8), 256, 0, stream>>>(dec_Whh, BwD);

    rnn_persist<<<NBLK, TPB, 0, stream>>>(
        x, BwE, BwD,
        enc_Wih, enc_bih, enc_bhh,
        dec_Wih, dec_bih, dec_bhh,
        fc_W, fc_b, out);
}